// Round 3
// baseline (495.283 us; speedup 1.0000x reference)
//
#include <hip/hip_runtime.h>
#include <hip/hip_bf16.h>

#define NE   64
#define NH   1024
#define NF   2816
#define TPE  64
#define BK   64
#define PITCH 72      // k2 LDS pitch (unchanged, validated)
#define K1BUF 12288   // ushorts per k1 LDS buffer (3 matrices x 64x64 bf16 = 24 KB)

typedef __attribute__((ext_vector_type(8))) short bf16x8;
typedef __attribute__((ext_vector_type(4))) float f32x4;

__device__ __forceinline__ ushort f2bf(float f) {
    union { float f; unsigned u; } v; v.f = f;
    unsigned r = v.u + 0x7fffu + ((v.u >> 16) & 1u);
    return (ushort)(r >> 16);
}

// convert two f32x4 (lo = k+0..3, hi = k+4..7) into one bf16x8 fragment
__device__ __forceinline__ bf16x8 cvt8(f32x4 lo, f32x4 hi) {
    bf16x8 r;
    #pragma unroll
    for (int j = 0; j < 4; ++j) {
        r[j]     = (short)f2bf(lo[j]);
        r[4 + j] = (short)f2bf(hi[j]);
    }
    return r;
}

// ---------------- Kernel 1: gated = silu(x@w1^T) * (x@w3^T), bf16 out ----------
// grid: (NF/64, NE), block 256 (4 waves). Tile: M=64 tokens x N=64 ff-cols.
// Reg-staged, double-buffered bf16 LDS, ONE barrier per K-step:
//   issue loads(kt+1) -> compute buf[kt&1] -> cvt+ds_write buf[(kt+1)&1] -> barrier
// LDS layout per matrix: [row][64 bf16], 16B slot swizzle slot' = c8 ^ (row&7)
// (write-side and read-side identical involution -> conflict-free both ways).
__global__ __launch_bounds__(256, 3)
void k1_gate(const float* __restrict__ x,
             const float* __restrict__ w1,
             const float* __restrict__ w3,
             ushort* __restrict__ g) {
    __shared__ ushort lds[2 * K1BUF];   // 48 KB -> 3 blocks/CU

    const int jt   = blockIdx.x;
    const int e    = blockIdx.y;
    const int tid  = threadIdx.x;
    const int lane = tid & 63;
    const int wid  = tid >> 6;
    const int m15  = lane & 15;
    const int hi   = lane >> 4;
    const int mrow = wid * 16 + m15;

    const float* xA = x  + (size_t)e * TPE * NH;
    const float* B1 = w1 + ((size_t)e * NF + (size_t)jt * 64) * NH;
    const float* B3 = w3 + ((size_t)e * NF + (size_t)jt * 64) * NH;

    // per-thread staging assignment: two 16B slots per matrix: tid and tid+256
    const int row0 = tid >> 3;               // slot0 row (0..31)
    const int c80  = tid & 7;                // slot0 col-octet
    const int row1 = row0 + 32;              // slot1 row (32..63)
    const int wo0  = row0 * 64 + ((c80 ^ (row0 & 7)) << 3);   // swizzled write offs
    const int wo1  = row1 * 64 + ((c80 ^ (row1 & 7)) << 3);
    const size_t go0 = (size_t)row0 * NH + c80 * 8;           // global offs (pre-kt)
    const size_t go1 = (size_t)row1 * NH + c80 * 8;

    f32x4 acc1[4], acc3[4];
    #pragma unroll
    for (int nf = 0; nf < 4; ++nf) {
        acc1[nf] = f32x4{0.f, 0.f, 0.f, 0.f};
        acc3[nf] = f32x4{0.f, 0.f, 0.f, 0.f};
    }

    f32x4 r[12];
    #define ISSUE_LOADS(kt)                                                     \
        do {                                                                    \
            const size_t kb = (size_t)(kt) * BK;                                \
            r[0]  = *(const f32x4*)(xA + go0 + kb);                             \
            r[1]  = *(const f32x4*)(xA + go0 + kb + 4);                         \
            r[2]  = *(const f32x4*)(xA + go1 + kb);                             \
            r[3]  = *(const f32x4*)(xA + go1 + kb + 4);                         \
            r[4]  = *(const f32x4*)(B1 + go0 + kb);                             \
            r[5]  = *(const f32x4*)(B1 + go0 + kb + 4);                         \
            r[6]  = *(const f32x4*)(B1 + go1 + kb);                             \
            r[7]  = *(const f32x4*)(B1 + go1 + kb + 4);                         \
            r[8]  = *(const f32x4*)(B3 + go0 + kb);                             \
            r[9]  = *(const f32x4*)(B3 + go0 + kb + 4);                         \
            r[10] = *(const f32x4*)(B3 + go1 + kb);                             \
            r[11] = *(const f32x4*)(B3 + go1 + kb + 4);                         \
        } while (0)

    #define WRITE_STAGE(buf)                                                    \
        do {                                                                    \
            *(bf16x8*)((buf) + wo0)            = cvt8(r[0],  r[1]);             \
            *(bf16x8*)((buf) + wo1)            = cvt8(r[2],  r[3]);             \
            *(bf16x8*)((buf) + 4096 + wo0)     = cvt8(r[4],  r[5]);             \
            *(bf16x8*)((buf) + 4096 + wo1)     = cvt8(r[6],  r[7]);             \
            *(bf16x8*)((buf) + 8192 + wo0)     = cvt8(r[8],  r[9]);             \
            *(bf16x8*)((buf) + 8192 + wo1)     = cvt8(r[10], r[11]);            \
        } while (0)

    // prologue: stage tile 0 into buffer 0
    ISSUE_LOADS(0);
    WRITE_STAGE(lds);
    __syncthreads();

    for (int kt = 0; kt < NH / BK; ++kt) {   // 16 iters, ONE barrier each
        const int ktn = (kt + 1 < NH / BK) ? kt + 1 : NH / BK - 1;  // clamp (last redundant)
        ISSUE_LOADS(ktn);                                    // in flight during compute

        const ushort* rb = lds + (kt & 1) * K1BUF;
        #pragma unroll
        for (int ks = 0; ks < 2; ++ks) {
            const int sa = ((ks * 4 + hi) ^ (mrow & 7)) << 3;
            const bf16x8 af = *(const bf16x8*)(rb + mrow * 64 + sa);
            #pragma unroll
            for (int nf = 0; nf < 4; ++nf) {
                const int brow = nf * 16 + m15;
                const int sb = ((ks * 4 + hi) ^ (brow & 7)) << 3;
                const bf16x8 b1 = *(const bf16x8*)(rb + 4096 + brow * 64 + sb);
                acc1[nf] = __builtin_amdgcn_mfma_f32_16x16x32_bf16(af, b1, acc1[nf], 0, 0, 0);
                const bf16x8 b3 = *(const bf16x8*)(rb + 8192 + brow * 64 + sb);
                acc3[nf] = __builtin_amdgcn_mfma_f32_16x16x32_bf16(af, b3, acc3[nf], 0, 0, 0);
            }
        }

        ushort* wb = lds + ((kt + 1) & 1) * K1BUF;
        WRITE_STAGE(wb);      // compiler waits vmcnt as needed; writes buffer all
        __syncthreads();      // waves finished reading one barrier ago
    }
    #undef ISSUE_LOADS
    #undef WRITE_STAGE

    // epilogue: SwiGLU, write bf16 gated. C/D layout: col=lane&15, row=(lane>>4)*4+i
    #pragma unroll
    for (int nf = 0; nf < 4; ++nf) {
        #pragma unroll
        for (int i = 0; i < 4; ++i) {
            const float h1v = acc1[nf][i];
            const float h3v = acc3[nf][i];
            const float s   = (h1v / (1.f + __expf(-h1v))) * h3v;
            const int row = wid * 16 + (hi * 4) + i;
            const int col = jt * 64 + nf * 16 + m15;
            const size_t t = (size_t)e * TPE + row;
            g[t * NF + col] = f2bf(s);
        }
    }
}

// ---------------- Kernel 2: out = gated @ w2 (per expert), fp32 out ------------
// (unchanged — measured ~104 us, at/below its ~125 us HBM floor)
__global__ __launch_bounds__(256, 2)
void k2_down(const ushort* __restrict__ g,
             const float* __restrict__ w2,
             float* __restrict__ out) {
    __shared__ ushort lA[64 * PITCH];
    __shared__ ushort lB[64 * PITCH];

    const int jt   = blockIdx.x;
    const int e    = blockIdx.y;
    const int tid  = threadIdx.x;
    const int lane = tid & 63;
    const int wid  = tid >> 6;

    const ushort* A = g  + (size_t)e * TPE * NF;
    const float*  B = w2 + (size_t)e * NF * NH + (size_t)jt * 64;
    float* O = out + (size_t)e * TPE * NH + (size_t)jt * 64;

    f32x4 acc[4];
    for (int nf = 0; nf < 4; ++nf) acc[nf] = f32x4{0.f, 0.f, 0.f, 0.f};

    for (int kt = 0; kt < NF / BK; ++kt) {   // 44 iters
        __syncthreads();
        #pragma unroll
        for (int r = 0; r < 2; ++r) {
            const int q   = tid + r * 256;
            const int row = q >> 3;
            const int k8  = (q & 7) * 8;
            *(bf16x8*)(&lA[row * PITCH + k8]) =
                *(const bf16x8*)(A + (size_t)row * NF + kt * BK + k8);
        }
        {
            const int n  = tid & 63;
            const int kq = (tid >> 6) * 4;
            #pragma unroll
            for (int r = 0; r < 4; ++r) {
                const int ks = kq + r * 16;
                const size_t base = (size_t)(kt * BK + ks) * NH + n;
                const float f0 = B[base];
                const float f1 = B[base + NH];
                const float f2 = B[base + 2 * (size_t)NH];
                const float f3 = B[base + 3 * (size_t)NH];
                ushort4 b;
                b.x = f2bf(f0); b.y = f2bf(f1); b.z = f2bf(f2); b.w = f2bf(f3);
                *(ushort4*)(&lB[n * PITCH + ks]) = b;
            }
        }
        __syncthreads();

        const int mrow = wid * 16 + (lane & 15);
        #pragma unroll
        for (int ks = 0; ks < 2; ++ks) {
            const int koff = ks * 32 + ((lane >> 4) * 8);
            const bf16x8 af = *(const bf16x8*)(&lA[mrow * PITCH + koff]);
            #pragma unroll
            for (int nf = 0; nf < 4; ++nf) {
                const bf16x8 bfr = *(const bf16x8*)(&lB[(nf * 16 + (lane & 15)) * PITCH + koff]);
                acc[nf] = __builtin_amdgcn_mfma_f32_16x16x32_bf16(af, bfr, acc[nf], 0, 0, 0);
            }
        }
    }

    #pragma unroll
    for (int nf = 0; nf < 4; ++nf) {
        #pragma unroll
        for (int i = 0; i < 4; ++i) {
            const int row = wid * 16 + ((lane >> 4) * 4) + i;
            const int col = nf * 16 + (lane & 15);
            O[(size_t)row * NH + col] = acc[nf][i];
        }
    }
}

extern "C" void kernel_launch(void* const* d_in, const int* in_sizes, int n_in,
                              void* d_out, int out_size, void* d_ws, size_t ws_size,
                              hipStream_t stream) {
    const float* x  = (const float*)d_in[0];
    const float* w1 = (const float*)d_in[2];
    const float* w3 = (const float*)d_in[3];
    const float* w2 = (const float*)d_in[4];
    float* out = (float*)d_out;
    ushort* gated = (ushort*)d_ws;   // [T][F] bf16, 23.1 MB

    dim3 g1(NF / 64, NE);   // (44, 64)
    k1_gate<<<g1, dim3(256), 0, stream>>>(x, w1, w3, gated);

    dim3 g2(NH / 64, NE);   // (16, 64)
    k2_down<<<g2, dim3(256), 0, stream>>>(gated, w2, out);
}

// Round 4
// 489.515 us; speedup vs baseline: 1.0118x; 1.0118x over previous
//
#include <hip/hip_runtime.h>
#include <hip/hip_bf16.h>

#define NE   64
#define NH   1024
#define NF   2816
#define TPE  64
#define PITCH 72      // k2 LDS pitch (unchanged, validated)

typedef __attribute__((ext_vector_type(8))) short bf16x8;
typedef __attribute__((ext_vector_type(4))) float f32x4;

__device__ __forceinline__ ushort f2bf(float f) {
    union { float f; unsigned u; } v; v.f = f;
    unsigned r = v.u + 0x7fffu + ((v.u >> 16) & 1u);
    return (ushort)(r >> 16);
}

__device__ __forceinline__ bf16x8 cvt8(f32x4 lo, f32x4 hi) {
    bf16x8 r;
    #pragma unroll
    for (int j = 0; j < 4; ++j) {
        r[j]     = (short)f2bf(lo[j]);
        r[4 + j] = (short)f2bf(hi[j]);
    }
    return r;
}

#define GLOAD16(gsrc, ldst)                                                          \
    __builtin_amdgcn_global_load_lds(                                                \
        (const __attribute__((address_space(1))) void*)(gsrc),                       \
        (__attribute__((address_space(3))) void*)(ldst), 16, 0, 0)

// ---------------- Kernel 1: gated = silu(x@w1^T) * (x@w3^T), bf16 out ----------
// grid: (NE, NF/128) = (64, 22)  [expert-major -> same-expert blocks share XCD L2]
// block 256 (4 waves). Tile: M=64 tokens x N=128 ff-cols, BK=32.
// f32 tiles staged via global_load_lds (linear dest, pre-swizzled SOURCE:
// 16B slot col' = c ^ (row&7); read side probes the same involution).
// f32->bf16 conversion at fragment-load time.
__global__ __launch_bounds__(256, 4)
void k1_gate(const float* __restrict__ x,
             const float* __restrict__ w1,
             const float* __restrict__ w3,
             ushort* __restrict__ g) {
    __shared__ float lds[10240];   // 40 KB: x[0..2047] w1[2048..6143] w3[6144..10239]
    float* lX  = lds;
    float* lW1 = lds + 2048;
    float* lW3 = lds + 6144;

    const int e    = blockIdx.x;      // expert (XCD = e % 8)
    const int jtt  = blockIdx.y;      // ff 128-tile (0..21)
    const int tid  = threadIdx.x;
    const int lane = tid & 63;
    const int wid  = tid >> 6;
    const int m15  = lane & 15;
    const int hi   = lane >> 4;
    const int mrow = wid * 16 + m15;

    const float* xA = x  + (size_t)e * TPE * NH;
    const float* B1 = w1 + ((size_t)e * NF + (size_t)jtt * 128) * NH;
    const float* B3 = w3 + ((size_t)e * NF + (size_t)jtt * 128) * NH;

    f32x4 acc1[8], acc3[8];
    #pragma unroll
    for (int nf = 0; nf < 8; ++nf) {
        acc1[nf] = f32x4{0.f, 0.f, 0.f, 0.f};
        acc3[nf] = f32x4{0.f, 0.f, 0.f, 0.f};
    }

    // fragment-read swizzled slots (row&7 == m15&7 for both A and B rows)
    const int s0 = (2 * hi) ^ (m15 & 7);
    const int s1 = s0 ^ 1;

    for (int kt = 0; kt < NH / 32; ++kt) {   // 32 iters
        const size_t kb = (size_t)kt * 32;
        __syncthreads();   // readers done with buffer
        // x: 512 slots (64 rows x 8 octets), 2 insts/thread
        #pragma unroll
        for (int i = 0; i < 2; ++i) {
            const int S   = i * 256 + tid;
            const int row = S >> 3;
            const int cs  = (S & 7) ^ (row & 7);
            GLOAD16(xA + (size_t)row * NH + kb + cs * 4, lX + (S & ~63) * 4);
        }
        // w1/w3: 1024 slots (128 rows x 8 octets), 4 insts/thread each
        #pragma unroll
        for (int i = 0; i < 4; ++i) {
            const int S   = i * 256 + tid;
            const int row = S >> 3;
            const int cs  = (S & 7) ^ (row & 7);
            const size_t goff = (size_t)row * NH + kb + cs * 4;
            GLOAD16(B1 + goff, lW1 + (S & ~63) * 4);
            GLOAD16(B3 + goff, lW3 + (S & ~63) * 4);
        }
        __syncthreads();   // vmcnt(0) drain -> tiles landed

        const f32x4 a0 = *(const f32x4*)&lX[mrow * 32 + s0 * 4];
        const f32x4 a1 = *(const f32x4*)&lX[mrow * 32 + s1 * 4];
        const bf16x8 af = cvt8(a0, a1);
        #pragma unroll
        for (int nf = 0; nf < 8; ++nf) {
            const int brow = nf * 16 + m15;
            const f32x4 p0 = *(const f32x4*)&lW1[brow * 32 + s0 * 4];
            const f32x4 p1 = *(const f32x4*)&lW1[brow * 32 + s1 * 4];
            acc1[nf] = __builtin_amdgcn_mfma_f32_16x16x32_bf16(af, cvt8(p0, p1), acc1[nf], 0, 0, 0);
            const f32x4 q0 = *(const f32x4*)&lW3[brow * 32 + s0 * 4];
            const f32x4 q1 = *(const f32x4*)&lW3[brow * 32 + s1 * 4];
            acc3[nf] = __builtin_amdgcn_mfma_f32_16x16x32_bf16(af, cvt8(q0, q1), acc3[nf], 0, 0, 0);
        }
    }

    // epilogue: SwiGLU, write bf16 gated. C/D layout: col=lane&15, row=(lane>>4)*4+i
    #pragma unroll
    for (int nf = 0; nf < 8; ++nf) {
        #pragma unroll
        for (int i = 0; i < 4; ++i) {
            const float h1v = acc1[nf][i];
            const float h3v = acc3[nf][i];
            const float s   = (h1v / (1.f + __expf(-h1v))) * h3v;
            const int row = wid * 16 + (hi * 4) + i;
            const int col = jtt * 128 + nf * 16 + m15;
            const size_t t = (size_t)e * TPE + row;
            g[t * NF + col] = f2bf(s);
        }
    }
}

// ---------------- Kernel 2: out = gated @ w2 (per expert), fp32 out ------------
// (unchanged — measured ~104 us, at/below its ~117 us HBM floor)
__global__ __launch_bounds__(256, 2)
void k2_down(const ushort* __restrict__ g,
             const float* __restrict__ w2,
             float* __restrict__ out) {
    __shared__ ushort lA[64 * PITCH];
    __shared__ ushort lB[64 * PITCH];

    const int jt   = blockIdx.x;
    const int e    = blockIdx.y;
    const int tid  = threadIdx.x;
    const int lane = tid & 63;
    const int wid  = tid >> 6;

    const ushort* A = g  + (size_t)e * TPE * NF;
    const float*  B = w2 + (size_t)e * NF * NH + (size_t)jt * 64;
    float* O = out + (size_t)e * TPE * NH + (size_t)jt * 64;

    f32x4 acc[4];
    for (int nf = 0; nf < 4; ++nf) acc[nf] = f32x4{0.f, 0.f, 0.f, 0.f};

    for (int kt = 0; kt < NF / 64; ++kt) {   // 44 iters
        __syncthreads();
        #pragma unroll
        for (int r = 0; r < 2; ++r) {
            const int q   = tid + r * 256;
            const int row = q >> 3;
            const int k8  = (q & 7) * 8;
            *(bf16x8*)(&lA[row * PITCH + k8]) =
                *(const bf16x8*)(A + (size_t)row * NF + kt * 64 + k8);
        }
        {
            const int n  = tid & 63;
            const int kq = (tid >> 6) * 4;
            #pragma unroll
            for (int r = 0; r < 4; ++r) {
                const int ks = kq + r * 16;
                const size_t base = (size_t)(kt * 64 + ks) * NH + n;
                const float f0 = B[base];
                const float f1 = B[base + NH];
                const float f2 = B[base + 2 * (size_t)NH];
                const float f3 = B[base + 3 * (size_t)NH];
                ushort4 b;
                b.x = f2bf(f0); b.y = f2bf(f1); b.z = f2bf(f2); b.w = f2bf(f3);
                *(ushort4*)(&lB[n * PITCH + ks]) = b;
            }
        }
        __syncthreads();

        const int mrow = wid * 16 + (lane & 15);
        #pragma unroll
        for (int ks = 0; ks < 2; ++ks) {
            const int koff = ks * 32 + ((lane >> 4) * 8);
            const bf16x8 af = *(const bf16x8*)(&lA[mrow * PITCH + koff]);
            #pragma unroll
            for (int nf = 0; nf < 4; ++nf) {
                const bf16x8 bfr = *(const bf16x8*)(&lB[(nf * 16 + (lane & 15)) * PITCH + koff]);
                acc[nf] = __builtin_amdgcn_mfma_f32_16x16x32_bf16(af, bfr, acc[nf], 0, 0, 0);
            }
        }
    }

    #pragma unroll
    for (int nf = 0; nf < 4; ++nf) {
        #pragma unroll
        for (int i = 0; i < 4; ++i) {
            const int row = wid * 16 + ((lane >> 4) * 4) + i;
            const int col = nf * 16 + (lane & 15);
            O[(size_t)row * NH + col] = acc[nf][i];
        }
    }
}

extern "C" void kernel_launch(void* const* d_in, const int* in_sizes, int n_in,
                              void* d_out, int out_size, void* d_ws, size_t ws_size,
                              hipStream_t stream) {
    const float* x  = (const float*)d_in[0];
    const float* w1 = (const float*)d_in[2];
    const float* w3 = (const float*)d_in[3];
    const float* w2 = (const float*)d_in[4];
    float* out = (float*)d_out;
    ushort* gated = (ushort*)d_ws;   // [T][F] bf16, 23.1 MB

    dim3 g1(NE, NF / 128);   // (64, 22), expert-major
    k1_gate<<<g1, dim3(256), 0, stream>>>(x, w1, w3, gated);

    dim3 g2(NH / 64, NE);    // (16, 64)
    k2_down<<<g2, dim3(256), 0, stream>>>(gated, w2, out);
}

// Round 5
// 456.403 us; speedup vs baseline: 1.0852x; 1.0725x over previous
//
#include <hip/hip_runtime.h>
#include <hip/hip_bf16.h>

#define NE   64
#define NH   1024
#define NF   2816
#define TPE  64
#define PITCH 72      // k2 LDS pitch (unchanged, validated)

typedef __attribute__((ext_vector_type(8))) short bf16x8;
typedef __attribute__((ext_vector_type(4))) float f32x4;

__device__ __forceinline__ ushort f2bf(float f) {
    union { float f; unsigned u; } v; v.f = f;
    unsigned r = v.u + 0x7fffu + ((v.u >> 16) & 1u);
    return (ushort)(r >> 16);
}

__device__ __forceinline__ bf16x8 cvt8(f32x4 lo, f32x4 hi) {
    bf16x8 r;
    #pragma unroll
    for (int j = 0; j < 4; ++j) {
        r[j]     = (short)f2bf(lo[j]);
        r[4 + j] = (short)f2bf(hi[j]);
    }
    return r;
}

#define GLOAD16(gsrc, ldst)                                                          \
    __builtin_amdgcn_global_load_lds(                                                \
        (const __attribute__((address_space(1))) void*)(gsrc),                       \
        (__attribute__((address_space(3))) void*)(ldst), 16, 0, 0)

// ---------------- Kernel 0: x (f32) -> xb (bf16), one pass -----------------
__global__ __launch_bounds__(256)
void xcast(const float* __restrict__ x, ushort* __restrict__ xb) {
    const int i = blockIdx.x * 256 + threadIdx.x;   // 8 elems per thread
    const f32x4 a = *(const f32x4*)(x + (size_t)i * 8);
    const f32x4 b = *(const f32x4*)(x + (size_t)i * 8 + 4);
    *(bf16x8*)(xb + (size_t)i * 8) = cvt8(a, b);
}

// ---------------- Kernel 1: gated = silu(x@w1^T) * (x@w3^T), bf16 out ----------
// grid: (NE, NF/64) = (64, 44) expert-major -> same-expert blocks share an XCD L2
// block 256 (4 waves). Tile: M=64 tokens x N=64 ff-cols, BK=64 (R2 schedule).
// A staged as pre-cast bf16 (8KB/iter); w1/w3 staged f32 (16KB each), cvt at
// fragment load. global_load_lds linear dest + pre-swizzled SOURCE (rule 21):
//   x rows (8 slots):   slot' = c ^ (row&7)
//   w rows (16 slots):  slot' = c ^ (row&15)
__global__ __launch_bounds__(256, 4)
void k1_gate(const ushort* __restrict__ xb,
             const float* __restrict__ w1,
             const float* __restrict__ w3,
             ushort* __restrict__ g) {
    __shared__ float fbuf[10240];              // 40 KB -> 4 blocks/CU
    ushort* lX  = (ushort*)fbuf;               // 4096 ushorts (8 KB)
    float*  lW1 = fbuf + 2048;                 // 4096 f32 (16 KB)
    float*  lW3 = fbuf + 6144;                 // 4096 f32 (16 KB)

    const int e    = blockIdx.x;               // expert (XCD = e % 8)
    const int jt   = blockIdx.y;               // ff 64-tile (0..43)
    const int tid  = threadIdx.x;
    const int lane = tid & 63;
    const int wid  = tid >> 6;
    const int m15  = lane & 15;
    const int hi   = lane >> 4;
    const int mrow = wid * 16 + m15;

    const ushort* xA = xb + (size_t)e * TPE * NH;
    const float*  B1 = w1 + ((size_t)e * NF + (size_t)jt * 64) * NH;
    const float*  B3 = w3 + ((size_t)e * NF + (size_t)jt * 64) * NH;

    f32x4 acc1[4], acc3[4];
    #pragma unroll
    for (int nf = 0; nf < 4; ++nf) {
        acc1[nf] = f32x4{0.f, 0.f, 0.f, 0.f};
        acc3[nf] = f32x4{0.f, 0.f, 0.f, 0.f};
    }

    for (int kt = 0; kt < NH / 64; ++kt) {     // 16 iters (R2 cadence)
        const size_t kb = (size_t)kt * 64;
        __syncthreads();                        // readers done with buffer
        // x-bf16: 512 slots (64 rows x 8 slots), 2 insts/thread
        #pragma unroll
        for (int i = 0; i < 2; ++i) {
            const int S   = i * 256 + tid;
            const int row = S >> 3;
            const int cs  = (S & 7) ^ (row & 7);
            GLOAD16(xA + (size_t)row * NH + kb + cs * 8, lX + (S & ~63) * 8);
        }
        // w1/w3 f32: 1024 slots (64 rows x 16 slots), 4 insts/thread each
        #pragma unroll
        for (int i = 0; i < 4; ++i) {
            const int S   = i * 256 + tid;
            const int row = S >> 4;
            const int cs  = (S & 15) ^ (row & 15);
            const size_t goff = (size_t)row * NH + kb + cs * 4;
            GLOAD16(B1 + goff, lW1 + (S & ~63) * 4);
            GLOAD16(B3 + goff, lW3 + (S & ~63) * 4);
        }
        __syncthreads();                        // vmcnt(0) drain -> tiles landed

        #pragma unroll
        for (int ks = 0; ks < 2; ++ks) {
            // A: bf16 direct; slot (ks*4+hi) ^ (mrow&7) within 8-slot row
            const int sxa = ((ks * 4 + hi) ^ (mrow & 7)) << 3;   // ushort offset
            const bf16x8 af = *(const bf16x8*)(lX + mrow * 64 + sxa);
            const int c0 = ks * 8 + hi * 2;     // w 16B-slot col (f32 slots)
            #pragma unroll
            for (int nf = 0; nf < 4; ++nf) {
                const int brow = nf * 16 + m15;  // brow&15 == m15
                const int sa0 = (c0 ^ m15) << 2, sa1 = ((c0 + 1) ^ m15) << 2;
                const f32x4 p0 = *(const f32x4*)&lW1[brow * 64 + sa0];
                const f32x4 p1 = *(const f32x4*)&lW1[brow * 64 + sa1];
                acc1[nf] = __builtin_amdgcn_mfma_f32_16x16x32_bf16(af, cvt8(p0, p1), acc1[nf], 0, 0, 0);
                const f32x4 q0 = *(const f32x4*)&lW3[brow * 64 + sa0];
                const f32x4 q1 = *(const f32x4*)&lW3[brow * 64 + sa1];
                acc3[nf] = __builtin_amdgcn_mfma_f32_16x16x32_bf16(af, cvt8(q0, q1), acc3[nf], 0, 0, 0);
            }
        }
    }

    // epilogue: SwiGLU, bf16 gated. C/D layout: col=lane&15, row=(lane>>4)*4+i
    #pragma unroll
    for (int nf = 0; nf < 4; ++nf) {
        #pragma unroll
        for (int i = 0; i < 4; ++i) {
            const float h1v = acc1[nf][i];
            const float h3v = acc3[nf][i];
            const float s   = (h1v / (1.f + __expf(-h1v))) * h3v;
            const int row = wid * 16 + (hi * 4) + i;
            const int col = jt * 64 + nf * 16 + m15;
            const size_t t = (size_t)e * TPE + row;
            g[t * NF + col] = f2bf(s);
        }
    }
}

// ---------------- Kernel 2: out = gated @ w2 (per expert), fp32 out ------------
// (unchanged — measured ~104 us, at/below its ~115 us HBM floor)
__global__ __launch_bounds__(256, 2)
void k2_down(const ushort* __restrict__ g,
             const float* __restrict__ w2,
             float* __restrict__ out) {
    __shared__ ushort lA[64 * PITCH];
    __shared__ ushort lB[64 * PITCH];

    const int jt   = blockIdx.x;
    const int e    = blockIdx.y;
    const int tid  = threadIdx.x;
    const int lane = tid & 63;
    const int wid  = tid >> 6;

    const ushort* A = g  + (size_t)e * TPE * NF;
    const float*  B = w2 + (size_t)e * NF * NH + (size_t)jt * 64;
    float* O = out + (size_t)e * TPE * NH + (size_t)jt * 64;

    f32x4 acc[4];
    for (int nf = 0; nf < 4; ++nf) acc[nf] = f32x4{0.f, 0.f, 0.f, 0.f};

    for (int kt = 0; kt < NF / 64; ++kt) {   // 44 iters
        __syncthreads();
        #pragma unroll
        for (int r = 0; r < 2; ++r) {
            const int q   = tid + r * 256;
            const int row = q >> 3;
            const int k8  = (q & 7) * 8;
            *(bf16x8*)(&lA[row * PITCH + k8]) =
                *(const bf16x8*)(A + (size_t)row * NF + kt * 64 + k8);
        }
        {
            const int n  = tid & 63;
            const int kq = (tid >> 6) * 4;
            #pragma unroll
            for (int r = 0; r < 4; ++r) {
                const int ks = kq + r * 16;
                const size_t base = (size_t)(kt * 64 + ks) * NH + n;
                const float f0 = B[base];
                const float f1 = B[base + NH];
                const float f2 = B[base + 2 * (size_t)NH];
                const float f3 = B[base + 3 * (size_t)NH];
                ushort4 b;
                b.x = f2bf(f0); b.y = f2bf(f1); b.z = f2bf(f2); b.w = f2bf(f3);
                *(ushort4*)(&lB[n * PITCH + ks]) = b;
            }
        }
        __syncthreads();

        const int mrow = wid * 16 + (lane & 15);
        #pragma unroll
        for (int ks = 0; ks < 2; ++ks) {
            const int koff = ks * 32 + ((lane >> 4) * 8);
            const bf16x8 af = *(const bf16x8*)(&lA[mrow * PITCH + koff]);
            #pragma unroll
            for (int nf = 0; nf < 4; ++nf) {
                const bf16x8 bfr = *(const bf16x8*)(&lB[(nf * 16 + (lane & 15)) * PITCH + koff]);
                acc[nf] = __builtin_amdgcn_mfma_f32_16x16x32_bf16(af, bfr, acc[nf], 0, 0, 0);
            }
        }
    }

    #pragma unroll
    for (int nf = 0; nf < 4; ++nf) {
        #pragma unroll
        for (int i = 0; i < 4; ++i) {
            const int row = wid * 16 + ((lane >> 4) * 4) + i;
            const int col = nf * 16 + (lane & 15);
            O[(size_t)row * NH + col] = acc[nf][i];
        }
    }
}

extern "C" void kernel_launch(void* const* d_in, const int* in_sizes, int n_in,
                              void* d_out, int out_size, void* d_ws, size_t ws_size,
                              hipStream_t stream) {
    const float* x  = (const float*)d_in[0];
    const float* w1 = (const float*)d_in[2];
    const float* w3 = (const float*)d_in[3];
    const float* w2 = (const float*)d_in[4];
    float* out = (float*)d_out;
    ushort* gated = (ushort*)d_ws;                         // 23.1 MB
    ushort* xbf   = (ushort*)((char*)d_ws + (32u << 20));  // 8.4 MB @ +32MB

    xcast<<<dim3((TPE * NE * NH) / (256 * 8)), dim3(256), 0, stream>>>(x, xbf);

    dim3 g1(NE, NF / 64);    // (64, 44) expert-major
    k1_gate<<<g1, dim3(256), 0, stream>>>(xbf, w1, w3, gated);

    dim3 g2(NH / 64, NE);    // (16, 64)
    k2_down<<<g2, dim3(256), 0, stream>>>(gated, w2, out);
}

// Round 6
// 436.670 us; speedup vs baseline: 1.1342x; 1.0452x over previous
//
#include <hip/hip_runtime.h>
#include <hip/hip_bf16.h>

#define NE   64
#define NH   1024
#define NF   2816
#define TPE  64
#define PITCH 72      // k2 LDS pitch (unchanged, validated)
#define K1BUF 10240   // floats per k1 buffer: x-bf16 8KB + w1 16KB + w3 16KB = 40KB

typedef __attribute__((ext_vector_type(8))) short bf16x8;
typedef __attribute__((ext_vector_type(4))) float f32x4;

__device__ __forceinline__ ushort f2bf(float f) {
    union { float f; unsigned u; } v; v.f = f;
    unsigned r = v.u + 0x7fffu + ((v.u >> 16) & 1u);
    return (ushort)(r >> 16);
}

__device__ __forceinline__ bf16x8 cvt8(f32x4 lo, f32x4 hi) {
    bf16x8 r;
    #pragma unroll
    for (int j = 0; j < 4; ++j) {
        r[j]     = (short)f2bf(lo[j]);
        r[4 + j] = (short)f2bf(hi[j]);
    }
    return r;
}

#define GLOAD16(gsrc, ldst)                                                          \
    __builtin_amdgcn_global_load_lds(                                                \
        (const __attribute__((address_space(1))) void*)(gsrc),                       \
        (__attribute__((address_space(3))) void*)(ldst), 16, 0, 0)

// ---------------- Kernel 0: x (f32) -> xb (bf16), one pass -----------------
__global__ __launch_bounds__(256)
void xcast(const float* __restrict__ x, ushort* __restrict__ xb) {
    const int i = blockIdx.x * 256 + threadIdx.x;   // 8 elems per thread
    const f32x4 a = *(const f32x4*)(x + (size_t)i * 8);
    const f32x4 b = *(const f32x4*)(x + (size_t)i * 8 + 4);
    *(bf16x8*)(xb + (size_t)i * 8) = cvt8(a, b);
}

// ---------------- Kernel 1: gated = silu(x@w1^T) * (x@w3^T), bf16 out ----------
// grid: (NF/64, NE) = (44, 64) jt-major (sequential weight regions in dispatch
// order -> DRAM locality). block 256 (4 waves). M=64 x N=64, BK=64, 16 K-steps.
// DOUBLE-BUFFERED gload_lds pipeline with counted vmcnt (T4): one full tile
// (10 loads/wave) always in flight; s_waitcnt vmcnt(10) in steady state,
// vmcnt(0) only on the last iteration. Raw s_barriers (no compiler drain).
// Source pre-swizzle (rule 21): x rows (8 slots) slot'=c^(row&7);
// w rows (16 slots) slot'=c^(row&15). Read side probes the same involution.
__global__ __launch_bounds__(256, 2)
void k1_gate(const ushort* __restrict__ xb,
             const float* __restrict__ w1,
             const float* __restrict__ w3,
             ushort* __restrict__ g) {
    __shared__ float fbuf[2 * K1BUF];   // 80 KB -> 2 blocks/CU

    const int jt   = blockIdx.x;               // ff 64-tile (0..43)
    const int e    = blockIdx.y;               // expert
    const int tid  = threadIdx.x;
    const int lane = tid & 63;
    const int wid  = tid >> 6;
    const int m15  = lane & 15;
    const int hi   = lane >> 4;
    const int mrow = wid * 16 + m15;

    const ushort* xA = xb + (size_t)e * TPE * NH;
    const float*  B1 = w1 + ((size_t)e * NF + (size_t)jt * 64) * NH;
    const float*  B3 = w3 + ((size_t)e * NF + (size_t)jt * 64) * NH;

    f32x4 acc1[4], acc3[4];
    #pragma unroll
    for (int nf = 0; nf < 4; ++nf) {
        acc1[nf] = f32x4{0.f, 0.f, 0.f, 0.f};
        acc3[nf] = f32x4{0.f, 0.f, 0.f, 0.f};
    }

    // stage tile t into buffer b (10 gload_lds per thread)
    #define STAGE(t, b)                                                              \
        do {                                                                         \
            float* bb = fbuf + (b) * K1BUF;                                          \
            ushort* sX = (ushort*)bb;                                                \
            float*  sW1 = bb + 2048;                                                 \
            float*  sW3 = bb + 6144;                                                 \
            const size_t kb = (size_t)(t) * 64;                                      \
            _Pragma("unroll")                                                        \
            for (int i = 0; i < 2; ++i) {                                            \
                const int S   = i * 256 + tid;                                       \
                const int row = S >> 3;                                              \
                const int cs  = (S & 7) ^ (row & 7);                                 \
                GLOAD16(xA + (size_t)row * NH + kb + cs * 8, sX + (S & ~63) * 8);    \
            }                                                                        \
            _Pragma("unroll")                                                        \
            for (int i = 0; i < 4; ++i) {                                            \
                const int S   = i * 256 + tid;                                       \
                const int row = S >> 4;                                              \
                const int cs  = (S & 15) ^ (row & 15);                               \
                const size_t goff = (size_t)row * NH + kb + cs * 4;                  \
                GLOAD16(B1 + goff, sW1 + (S & ~63) * 4);                             \
                GLOAD16(B3 + goff, sW3 + (S & ~63) * 4);                             \
            }                                                                        \
        } while (0)

    // prologue: two tiles in flight
    STAGE(0, 0);
    STAGE(1, 1);

    #pragma unroll
    for (int kt = 0; kt < 16; ++kt) {
        // wait: tile kt landed (in-order retire); tile kt+1's 10 still in flight
        if (kt < 15) asm volatile("s_waitcnt vmcnt(10)" ::: "memory");
        else         asm volatile("s_waitcnt vmcnt(0)"  ::: "memory");
        __builtin_amdgcn_s_barrier();          // everyone's tile-kt data in LDS
        asm volatile("" ::: "memory");

        const float* bb = fbuf + (kt & 1) * K1BUF;
        const ushort* sX = (const ushort*)bb;
        const float*  sW1 = bb + 2048;
        const float*  sW3 = bb + 6144;

        #pragma unroll
        for (int ks = 0; ks < 2; ++ks) {
            const int sxa = ((ks * 4 + hi) ^ (mrow & 7)) << 3;
            const bf16x8 af = *(const bf16x8*)(sX + mrow * 64 + sxa);
            const int c0 = ks * 8 + hi * 2;
            #pragma unroll
            for (int nf = 0; nf < 4; ++nf) {
                const int brow = nf * 16 + m15;     // brow&15 == m15
                const int sa0 = (c0 ^ m15) << 2, sa1 = ((c0 + 1) ^ m15) << 2;
                const f32x4 p0 = *(const f32x4*)&sW1[brow * 64 + sa0];
                const f32x4 p1 = *(const f32x4*)&sW1[brow * 64 + sa1];
                acc1[nf] = __builtin_amdgcn_mfma_f32_16x16x32_bf16(af, cvt8(p0, p1), acc1[nf], 0, 0, 0);
                const f32x4 q0 = *(const f32x4*)&sW3[brow * 64 + sa0];
                const f32x4 q1 = *(const f32x4*)&sW3[brow * 64 + sa1];
                acc3[nf] = __builtin_amdgcn_mfma_f32_16x16x32_bf16(af, cvt8(q0, q1), acc3[nf], 0, 0, 0);
            }
        }

        asm volatile("" ::: "memory");
        __builtin_amdgcn_s_barrier();          // all waves done reading buf[kt&1]
        asm volatile("" ::: "memory");
        if (kt + 2 < 16) STAGE(kt + 2, kt & 1);  // refill the buffer just read
    }
    #undef STAGE

    // epilogue: SwiGLU, bf16 gated. C/D layout: col=lane&15, row=(lane>>4)*4+i
    #pragma unroll
    for (int nf = 0; nf < 4; ++nf) {
        #pragma unroll
        for (int i = 0; i < 4; ++i) {
            const float h1v = acc1[nf][i];
            const float h3v = acc3[nf][i];
            const float s   = (h1v / (1.f + __expf(-h1v))) * h3v;
            const int row = wid * 16 + (hi * 4) + i;
            const int col = jt * 64 + nf * 16 + m15;
            const size_t t = (size_t)e * TPE + row;
            g[t * NF + col] = f2bf(s);
        }
    }
}

// ---------------- Kernel 2: out = gated @ w2 (per expert), fp32 out ------------
// (unchanged — measured ~104 us, at/below its ~115 us HBM floor)
__global__ __launch_bounds__(256, 2)
void k2_down(const ushort* __restrict__ g,
             const float* __restrict__ w2,
             float* __restrict__ out) {
    __shared__ ushort lA[64 * PITCH];
    __shared__ ushort lB[64 * PITCH];

    const int jt   = blockIdx.x;
    const int e    = blockIdx.y;
    const int tid  = threadIdx.x;
    const int lane = tid & 63;
    const int wid  = tid >> 6;

    const ushort* A = g  + (size_t)e * TPE * NF;
    const float*  B = w2 + (size_t)e * NF * NH + (size_t)jt * 64;
    float* O = out + (size_t)e * TPE * NH + (size_t)jt * 64;

    f32x4 acc[4];
    for (int nf = 0; nf < 4; ++nf) acc[nf] = f32x4{0.f, 0.f, 0.f, 0.f};

    for (int kt = 0; kt < NF / 64; ++kt) {   // 44 iters
        __syncthreads();
        #pragma unroll
        for (int r = 0; r < 2; ++r) {
            const int q   = tid + r * 256;
            const int row = q >> 3;
            const int k8  = (q & 7) * 8;
            *(bf16x8*)(&lA[row * PITCH + k8]) =
                *(const bf16x8*)(A + (size_t)row * NF + kt * 64 + k8);
        }
        {
            const int n  = tid & 63;
            const int kq = (tid >> 6) * 4;
            #pragma unroll
            for (int r = 0; r < 4; ++r) {
                const int ks = kq + r * 16;
                const size_t base = (size_t)(kt * 64 + ks) * NH + n;
                const float f0 = B[base];
                const float f1 = B[base + NH];
                const float f2 = B[base + 2 * (size_t)NH];
                const float f3 = B[base + 3 * (size_t)NH];
                ushort4 b;
                b.x = f2bf(f0); b.y = f2bf(f1); b.z = f2bf(f2); b.w = f2bf(f3);
                *(ushort4*)(&lB[n * PITCH + ks]) = b;
            }
        }
        __syncthreads();

        const int mrow = wid * 16 + (lane & 15);
        #pragma unroll
        for (int ks = 0; ks < 2; ++ks) {
            const int koff = ks * 32 + ((lane >> 4) * 8);
            const bf16x8 af = *(const bf16x8*)(&lA[mrow * PITCH + koff]);
            #pragma unroll
            for (int nf = 0; nf < 4; ++nf) {
                const bf16x8 bfr = *(const bf16x8*)(&lB[(nf * 16 + (lane & 15)) * PITCH + koff]);
                acc[nf] = __builtin_amdgcn_mfma_f32_16x16x32_bf16(af, bfr, acc[nf], 0, 0, 0);
            }
        }
    }

    #pragma unroll
    for (int nf = 0; nf < 4; ++nf) {
        #pragma unroll
        for (int i = 0; i < 4; ++i) {
            const int row = wid * 16 + ((lane >> 4) * 4) + i;
            const int col = nf * 16 + (lane & 15);
            O[(size_t)row * NH + col] = acc[nf][i];
        }
    }
}

extern "C" void kernel_launch(void* const* d_in, const int* in_sizes, int n_in,
                              void* d_out, int out_size, void* d_ws, size_t ws_size,
                              hipStream_t stream) {
    const float* x  = (const float*)d_in[0];
    const float* w1 = (const float*)d_in[2];
    const float* w3 = (const float*)d_in[3];
    const float* w2 = (const float*)d_in[4];
    float* out = (float*)d_out;
    ushort* gated = (ushort*)d_ws;                         // 23.1 MB
    ushort* xbf   = (ushort*)((char*)d_ws + (32u << 20));  // 8.4 MB @ +32MB

    xcast<<<dim3((TPE * NE * NH) / (256 * 8)), dim3(256), 0, stream>>>(x, xbf);

    dim3 g1(NF / 64, NE);    // (44, 64) jt-major
    k1_gate<<<g1, dim3(256), 0, stream>>>(xbf, w1, w3, gated);

    dim3 g2(NH / 64, NE);    // (16, 64)
    k2_down<<<g2, dim3(256), 0, stream>>>(gated, w2, out);
}